// Round 3
// baseline (2335.936 us; speedup 1.0000x reference)
//
#include <hip/hip_runtime.h>
#include <math.h>

#define HH 56
#define WW 56
#define HWPX 3136        // 56*56
#define CC 448
#define NBANK 100
#define KIM 20
#define OUTHW 224
#define CCH 32           // c-chunk in kwin

__device__ __forceinline__ float dot4(float4 a, float4 b) {
  return a.x*b.x + a.y*b.y + a.z*b.z + a.w*b.w;
}

// ---------------- Kernel A: transpose (B,C,H,W) -> (B,HW,C) + per-pixel e2 ----
__global__ void ktrans(const float* __restrict__ emb, float* __restrict__ eT,
                       float* __restrict__ e2) {
  int t = blockIdx.x * blockDim.x + threadIdx.x;
  if (t >= 2 * HWPX) return;
  int b = t / HWPX, p = t - b * HWPX;
  const float* src = emb + (size_t)b * CC * HWPX + p;
  float* dst = eT + (size_t)t * CC;
  float acc = 0.f;
  #pragma unroll 4
  for (int c = 0; c < CC; c += 4) {
    float v0 = src[(size_t)(c + 0) * HWPX];
    float v1 = src[(size_t)(c + 1) * HWPX];
    float v2 = src[(size_t)(c + 2) * HWPX];
    float v3 = src[(size_t)(c + 3) * HWPX];
    acc += v0*v0 + v1*v1 + v2*v2 + v3*v3;
    *reinterpret_cast<float4*>(dst + c) = make_float4(v0, v1, v2, v3);
  }
  e2[t] = acc;
}

// ---------------- Kernel B: one streaming pass over memory bank --------------
// per-pixel m2 -> mrow2, per-row sum(m2) -> m2acc, dots e_b . m_n -> dotacc
__global__ void kpass1(const float* __restrict__ mb, const float* __restrict__ eT,
                       float* __restrict__ mrow2, float* __restrict__ dotacc,
                       float* __restrict__ m2acc) {
  int n = blockIdx.x / 98, chunk = blockIdx.x % 98;
  int wave = threadIdx.x >> 6, lane = threadIdx.x & 63;
  int p0 = chunk * 32 + wave * 8;
  const float4* m4 = reinterpret_cast<const float4*>(mb + (size_t)n * HWPX * CC);
  const float4* e4 = reinterpret_cast<const float4*>(eT);
  float d0 = 0.f, d1 = 0.f, m2s = 0.f;
  for (int i = 0; i < 8; ++i) {
    int p = p0 + i;
    const float4* mr  = m4 + (size_t)p * 112;
    const float4* er0 = e4 + (size_t)p * 112;
    const float4* er1 = e4 + (size_t)(HWPX + p) * 112;
    float m2 = 0.f;
    {
      float4 m = mr[lane], a = er0[lane], bb = er1[lane];
      m2 += dot4(m, m); d0 += dot4(m, a); d1 += dot4(m, bb);
    }
    if (lane < 48) {
      float4 m = mr[64 + lane], a = er0[64 + lane], bb = er1[64 + lane];
      m2 += dot4(m, m); d0 += dot4(m, a); d1 += dot4(m, bb);
    }
    #pragma unroll
    for (int s = 1; s < 64; s <<= 1) m2 += __shfl_xor(m2, s);
    if (lane == 0) { mrow2[(size_t)n * HWPX + p] = m2; m2s += m2; }
  }
  #pragma unroll
  for (int s = 1; s < 64; s <<= 1) { d0 += __shfl_xor(d0, s); d1 += __shfl_xor(d1, s); }
  if (lane == 0) {
    atomicAdd(&dotacc[n], d0);
    atomicAdd(&dotacc[NBANK + n], d1);
    atomicAdd(&m2acc[n], m2s);
  }
}

// ---------------- Kernel C: dist, top-20 (min), pred_score, gaussian weights --
__global__ void kselect(const float* __restrict__ m2acc, const float* __restrict__ e2,
                        const float* __restrict__ dotacc, int* __restrict__ topidx,
                        float* __restrict__ gw, float* __restrict__ pred) {
  __shared__ float s_m2[NBANK];
  __shared__ float s_e2t[2];
  int wave = threadIdx.x >> 6, lane = threadIdx.x & 63;
  if (threadIdx.x < NBANK) s_m2[threadIdx.x] = m2acc[threadIdx.x];
  if (wave < 2) {
    float s = 0.f;
    for (int i = lane; i < HWPX; i += 64) s += e2[wave * HWPX + i];
    #pragma unroll
    for (int m = 1; m < 64; m <<= 1) s += __shfl_xor(s, m);
    if (lane == 0) s_e2t[wave] = s;
  }
  __syncthreads();
  if (threadIdx.x == 0) {
    float wsum = 0.f, wv[33];
    for (int t = 0; t < 33; ++t) {
      float x = (t - 16) * 0.25f;            // (t-R)/SIGMA
      wv[t] = expf(-0.5f * x * x);
      wsum += wv[t];
    }
    for (int t = 0; t < 33; ++t) gw[t] = wv[t] / wsum;
  }
  if (wave < 2) {
    int b = wave;
    float e2t = s_e2t[b];
    float va = 1e30f, vb = 1e30f;
    if (lane < NBANK) {
      float d2 = e2t + s_m2[lane] - 2.f * dotacc[b * NBANK + lane];
      va = sqrtf(fmaxf(d2, 0.f));
    }
    if (lane + 64 < NBANK) {
      float d2 = e2t + s_m2[lane + 64] - 2.f * dotacc[b * NBANK + lane + 64];
      vb = sqrtf(fmaxf(d2, 0.f));
    }
    float sum = 0.f;
    for (int k = 0; k < KIM; ++k) {
      float v = va; int id = lane;
      if (vb < v) { v = vb; id = lane + 64; }
      #pragma unroll
      for (int m = 1; m < 64; m <<= 1) {
        float ov = __shfl_xor(v, m);
        int  oid = __shfl_xor(id, m);
        if (ov < v || (ov == v && oid < id)) { v = ov; id = oid; }
      }
      sum += v;
      if (lane == 0) topidx[b * KIM + k] = id;
      if (id < 64) { if (lane == id) va = 1e30f; }
      else         { if (lane == id - 64) vb = 1e30f; }
    }
    if (lane == 0) pred[b] = sum * (1.f / KIM);
  }
}

// ---------------- Kernel D: windowed NN re-rank ------------------------------
// block decode: h innermost so 56 consecutive blocks share one bank row n
// (80% overlap of the staged 5-row window between h-neighbors -> L2 hits).
// 5 waves = dy; lanes = w. LDS-staged, XOR-swizzled.
__global__ __launch_bounds__(320) void kwin(const float* __restrict__ mb,
                     const float* __restrict__ eT, const float* __restrict__ mrow2,
                     const float* __restrict__ e2, const int* __restrict__ topidx,
                     float* __restrict__ best) {
  int bid = blockIdx.x;
  int h = bid % HH;
  int k = (bid / HH) % KIM;
  int b = bid / (HH * KIM);
  int n = topidx[b * KIM + k];
  int dy = threadIdx.x >> 6;       // 0..4
  int lane = threadIdx.x & 63;     // w when < 56
  int hp = h + dy - 2;
  bool rowok = (hp >= 0) && (hp < HH);
  __shared__ float4 lds_m4[5 * 60 * 8];   // 38400 B, swizzled
  __shared__ float4 lds_e4[56 * 8];       //  7168 B, swizzled
  __shared__ unsigned s_best[WW];
  if (threadIdx.x < WW) s_best[threadIdx.x] = 0x7f7f7f7fu;
  float* lds_m = reinterpret_cast<float*>(lds_m4);
  float* lds_e = reinterpret_cast<float*>(lds_e4);
  const float* mrow = mb + (size_t)n * HWPX * CC;
  const float* erow = eT + ((size_t)b * HWPX + h * WW) * CC;
  int seg = threadIdx.x >> 5;      // 0..9 (half-wave id)
  int cl  = threadIdx.x & 31;      // channel-in-chunk
  float acc[5] = {0.f, 0.f, 0.f, 0.f, 0.f};
  for (int c0 = 0; c0 < CC; c0 += CCH) {
    // stage m: 5 rows x 60 cols (w' = -2..57) x 32 channels, OOB -> 0
    #pragma unroll
    for (int it = 0; it < 30; ++it) {
      int pair = it * 10 + seg;
      int hh2 = pair / 60;
      int wp = pair - hh2 * 60;
      int h2 = h + hh2 - 2;
      int w2 = wp - 2;
      float v = 0.f;
      if (h2 >= 0 && h2 < HH && w2 >= 0 && w2 < WW)
        v = mrow[(size_t)(h2 * WW + w2) * CC + c0 + cl];
      int j = cl >> 2;
      lds_m[(pair * 8 + (j ^ (pair & 7))) * 4 + (cl & 3)] = v;
    }
    // stage e: 56 rows x 32 channels
    #pragma unroll
    for (int it = 0; it < 6; ++it) {
      int pair = it * 10 + seg;
      if (pair < WW) {
        float v = erow[(size_t)pair * CC + c0 + cl];
        int j = cl >> 2;
        lds_e[(pair * 8 + (j ^ (pair & 7))) * 4 + (cl & 3)] = v;
      }
    }
    __syncthreads();
    if (lane < WW) {
      #pragma unroll
      for (int j = 0; j < 8; ++j) {
        float4 ev = lds_e4[lane * 8 + (j ^ (lane & 7))];
        #pragma unroll
        for (int dx = 0; dx < 5; ++dx) {
          int row = dy * 60 + lane + dx;
          float4 mv = lds_m4[row * 8 + (j ^ (row & 7))];
          acc[dx] += dot4(ev, mv);
        }
      }
    }
    __syncthreads();
  }
  if (rowok && lane < WW) {
    float e2v = e2[b * HWPX + h * WW + lane];
    float lbest = 1e30f;
    #pragma unroll
    for (int dx = 0; dx < 5; ++dx) {
      int w2 = lane + dx - 2;
      if (w2 >= 0 && w2 < WW) {
        float m2v = mrow2[(size_t)n * HWPX + hp * WW + w2];
        float d2w = fmaxf(e2v + m2v - 2.f * acc[dx], 0.f);
        lbest = fminf(lbest, d2w);
      }
    }
    if (lbest < 1e30f) atomicMin(&s_best[lane], __float_as_uint(lbest));
  }
  __syncthreads();
  if (threadIdx.x < WW) {
    unsigned v = s_best[threadIdx.x];
    if (v != 0x7f7f7f7fu)
      atomicMin(reinterpret_cast<unsigned*>(&best[b * HWPX + h * WW + threadIdx.x]), v);
  }
}

// ---------------- Kernel E1: sqrt + bilinear 56 -> 224 -----------------------
__global__ void kresize(const float* __restrict__ best, float* __restrict__ rsz) {
  int t = blockIdx.x * blockDim.x + threadIdx.x;
  if (t >= 2 * OUTHW * OUTHW) return;
  int b = t / (OUTHW * OUTHW), r = t - b * OUTHW * OUTHW;
  int oy = r / OUTHW, ox = r - oy * OUTHW;
  float ys = (oy + 0.5f) * 0.25f - 0.5f;
  float xs = (ox + 0.5f) * 0.25f - 0.5f;
  float yf = floorf(ys), xf = floorf(xs);
  float fy = ys - yf, fx = xs - xf;
  int y0 = (int)yf, x0 = (int)xf;
  int y0c = y0 < 0 ? 0 : y0;        int y1c = y0 + 1 > 55 ? 55 : (y0 + 1 < 0 ? 0 : y0 + 1);
  int x0c = x0 < 0 ? 0 : x0;        int x1c = x0 + 1 > 55 ? 55 : (x0 + 1 < 0 ? 0 : x0 + 1);
  const float* bb = best + b * HWPX;
  float v00 = sqrtf(bb[y0c * WW + x0c]);
  float v01 = sqrtf(bb[y0c * WW + x1c]);
  float v10 = sqrtf(bb[y1c * WW + x0c]);
  float v11 = sqrtf(bb[y1c * WW + x1c]);
  float v0 = v00 + (v01 - v00) * fx;
  float v1 = v10 + (v11 - v10) * fx;
  rsz[t] = v0 + (v1 - v0) * fy;
}

// ---------------- Kernel E2/E3: separable Gaussian blur (reflect) ------------
__global__ void kblurv(const float* __restrict__ in, const float* __restrict__ gw,
                       float* __restrict__ o) {
  int t = blockIdx.x * blockDim.x + threadIdx.x;
  if (t >= 2 * OUTHW * OUTHW) return;
  int b = t / (OUTHW * OUTHW), r = t - b * OUTHW * OUTHW;
  int y = r / OUTHW, x = r - y * OUTHW;
  float s = 0.f;
  #pragma unroll
  for (int u = -16; u <= 16; ++u) {
    int yy = y + u;
    yy = yy < 0 ? -yy : (yy > 223 ? 446 - yy : yy);
    s += gw[u + 16] * in[b * OUTHW * OUTHW + yy * OUTHW + x];
  }
  o[t] = s;
}

__global__ void kblurh(const float* __restrict__ in, const float* __restrict__ gw,
                       float* __restrict__ o) {
  int t = blockIdx.x * blockDim.x + threadIdx.x;
  if (t >= 2 * OUTHW * OUTHW) return;
  int b = t / (OUTHW * OUTHW), r = t - b * OUTHW * OUTHW;
  int y = r / OUTHW, x = r - y * OUTHW;
  float s = 0.f;
  #pragma unroll
  for (int u = -16; u <= 16; ++u) {
    int xx = x + u;
    xx = xx < 0 ? -xx : (xx > 223 ? 446 - xx : xx);
    s += gw[u + 16] * in[b * OUTHW * OUTHW + y * OUTHW + xx];
  }
  o[t] = s;
}

// ---------------- launch -----------------------------------------------------
extern "C" void kernel_launch(void* const* d_in, const int* in_sizes, int n_in,
                              void* d_out, int out_size, void* d_ws, size_t ws_size,
                              hipStream_t stream) {
  const float* emb   = (const float*)d_in[0];
  const float* mbank = (const float*)d_in[1];
  float* out = (float*)d_out;
  float* ws  = (float*)d_ws;

  size_t off = 0;
  float* eT     = ws + off; off += (size_t)2 * HWPX * CC;   // 2,809,856
  float* e2     = ws + off; off += 2 * HWPX;                // 6,272
  float* mrow2  = ws + off; off += (size_t)NBANK * HWPX;    // 313,600
  float* dotacc = ws + off; off += 2 * NBANK;               // 200  (zeroed)
  float* m2acc  = ws + off; off += NBANK;                   // 100  (zeroed)
  int*   topidx = (int*)(ws + off); off += 2 * KIM;         // 40
  float* gw     = ws + off; off += 34;                      // 33 + pad
  float* best   = ws + off; off += 2 * HWPX;                // 6,272 (memset 0x7f)
  float* rsz    = ws + off; off += (size_t)2 * OUTHW * OUTHW;
  float* tmp    = ws + off; off += (size_t)2 * OUTHW * OUTHW;
  // total ~13.4 MB of workspace

  hipMemsetAsync(dotacc, 0, (2 * NBANK + NBANK) * sizeof(float), stream);
  hipMemsetAsync(best, 0x7f, 2 * HWPX * sizeof(float), stream);  // 0x7f7f7f7f ~ 3.4e38

  hipLaunchKernelGGL(ktrans, dim3((2 * HWPX + 255) / 256), dim3(256), 0, stream,
                     emb, eT, e2);
  hipLaunchKernelGGL(kpass1, dim3(NBANK * 98), dim3(256), 0, stream,
                     mbank, eT, mrow2, dotacc, m2acc);
  hipLaunchKernelGGL(kselect, dim3(1), dim3(256), 0, stream,
                     m2acc, e2, dotacc, topidx, gw, out);
  hipLaunchKernelGGL(kwin, dim3(2 * HH * KIM), dim3(320), 0, stream,
                     mbank, eT, mrow2, e2, topidx, best);
  int npix = 2 * OUTHW * OUTHW;
  hipLaunchKernelGGL(kresize, dim3((npix + 255) / 256), dim3(256), 0, stream, best, rsz);
  hipLaunchKernelGGL(kblurv, dim3((npix + 255) / 256), dim3(256), 0, stream, rsz, gw, tmp);
  hipLaunchKernelGGL(kblurh, dim3((npix + 255) / 256), dim3(256), 0, stream, tmp, gw, out + 2);
}